// Round 1
// 485.184 us; speedup vs baseline: 1.0145x; 1.0145x over previous
//
#include <hip/hip_runtime.h>

#define TWO_PI_F 6.28318530717958647692f
#define SCL_F    0.02209708691207961f   // TEMP/SCALE/sqrt(128)

__device__ __forceinline__ float rlane(float v, int l) {
    return __uint_as_float((unsigned)__builtin_amdgcn_readlane((int)__float_as_uint(v), l));
}

// ---------------------------------------------------------------------------
// Group-norm partial stats for in_f: per (b,g) over 16384 rows x 32 ch.
// grid=(64,32), block=256
// ---------------------------------------------------------------------------
__global__ __launch_bounds__(256) void gn_partial_k(const float* __restrict__ X,
                                                    float* __restrict__ partials)
{
    int t = threadIdx.x;
    int chunk = blockIdx.x;
    int grp = blockIdx.y;          // b*4+g
    int b = grp >> 2, g = grp & 3;
    const float* base = X + ((long)b * 16384 + (long)chunk * 256) * 128 + g * 32;
    float s = 0.f, ss = 0.f;
#pragma unroll
    for (int i = 0; i < 8; i++) {
        int rl_ = i * 32 + (t >> 3);
        int c4 = (t & 7) * 4;
        float4 v = *(const float4*)(base + (long)rl_ * 128 + c4);
        s  += v.x + v.y + v.z + v.w;
        ss += v.x * v.x + v.y * v.y + v.z * v.z + v.w * v.w;
    }
    __shared__ float r0[256], r1[256];
    r0[t] = s; r1[t] = ss;
    __syncthreads();
    for (int off = 128; off > 0; off >>= 1) {
        if (t < off) { r0[t] += r0[t + off]; r1[t] += r1[t + off]; }
        __syncthreads();
    }
    if (t == 0) {
        partials[(grp * 64 + chunk) * 2]     = r0[0];
        partials[(grp * 64 + chunk) * 2 + 1] = r1[0];
    }
}

// grid=32, block=64; nblk partials per group
__global__ void gn_final_k(const float* __restrict__ partials, float* __restrict__ stats,
                           int nblk)
{
    int grp = blockIdx.x, t = threadIdx.x;
    float s = 0.f, ss = 0.f;
    for (int i = t; i < nblk; i += 64) {
        s  += partials[(grp * nblk + i) * 2];
        ss += partials[(grp * nblk + i) * 2 + 1];
    }
    for (int off = 1; off < 64; off <<= 1) { s += __shfl_xor(s, off); ss += __shfl_xor(ss, off); }
    if (t == 0) {
        const float N = 524288.0f;
        float mu = s / N;
        float var = ss / N - mu * mu;
        stats[grp * 2]     = mu;
        stats[grp * 2 + 1] = 1.0f / sqrtf(var + 0.001f);
    }
}

// ---------------------------------------------------------------------------
// Wvf = Wv @ Wfc  (128x128). grid=32 blocks x 256 threads (4 rows/block).
// ---------------------------------------------------------------------------
__global__ __launch_bounds__(256) void wvf_prep_k(const float* __restrict__ Wv,
                                                  const float* __restrict__ Wfc,
                                                  float* __restrict__ out)
{
    int t = threadIdx.x;
    int rr = t >> 6, cl = t & 63;
    int r = blockIdx.x * 4 + rr;
    float a0 = 0.f, a1 = 0.f;
    for (int k = 0; k < 128; k++) {
        float wv = Wv[r * 128 + k];
        a0 = fmaf(wv, Wfc[k * 128 + cl], a0);
        a1 = fmaf(wv, Wfc[k * 128 + 64 + cl], a1);
    }
    out[r * 128 + cl] = a0;
    out[r * 128 + 64 + cl] = a1;
}

// ---------------------------------------------------------------------------
// C[M,128] = act( gn(X) @ W + bias ), M=131072.
// grid=1024 (128 rows/block), block=128, per-thread 8x16 tile.
// cols of thread = cg*4 + 32m (m=0..3)  -> conflict-free b128 B reads.
// sA stored transposed [k][row] stride 132; sB [k][col] stride 132.
// Optional fused group-stats output (for qraw: bias=null, leaky=0).
// ---------------------------------------------------------------------------
__global__ __launch_bounds__(128, 2) void gemm128_v2(const float* __restrict__ X,
                                                     const float* __restrict__ W,
                                                     const float* __restrict__ bias,
                                                     const float* __restrict__ stats,
                                                     float* __restrict__ C, int leaky,
                                                     float* __restrict__ statsout)
{
    __shared__ float sA[32 * 132];
    __shared__ float sB[32 * 132];
    __shared__ float sRed[128 * 8];
    int t = threadIdx.x;
    long row0 = (long)blockIdx.x * 128;
    int bidx = (int)(row0 >> 14);

    float muv[4], rsv[4];
#pragma unroll
    for (int g = 0; g < 4; g++) {
        muv[g] = stats ? stats[(bidx * 4 + g) * 2]     : 0.f;
        rsv[g] = stats ? stats[(bidx * 4 + g) * 2 + 1] : 1.f;
    }
    int rg = t >> 3, cg = t & 7;
    float acc[8][16];
#pragma unroll
    for (int i = 0; i < 8; i++)
#pragma unroll
        for (int j = 0; j < 16; j++) acc[i][j] = 0.f;

    const float* xs = X + (row0 + t) * 128;
    int kb = t >> 2, c0 = (t & 3) * 32;

    for (int kt = 0; kt < 4; kt++) {
        // stage A transposed + normalized (k-range [32kt,32kt+32) == group kt)
        float mu = muv[kt], rs = rsv[kt];
        const float* asrc = xs + kt * 32;
#pragma unroll
        for (int q = 0; q < 8; q++) {
            float4 v = *(const float4*)(asrc + 4 * q);
            sA[(4 * q + 0) * 132 + t] = (v.x - mu) * rs;
            sA[(4 * q + 1) * 132 + t] = (v.y - mu) * rs;
            sA[(4 * q + 2) * 132 + t] = (v.z - mu) * rs;
            sA[(4 * q + 3) * 132 + t] = (v.w - mu) * rs;
        }
        // stage B
        const float* bsrc = W + (long)(kt * 32 + kb) * 128 + c0;
#pragma unroll
        for (int q = 0; q < 8; q++)
            *(float4*)&sB[kb * 132 + c0 + 4 * q] = *(const float4*)(bsrc + 4 * q);
        __syncthreads();
#pragma unroll 4
        for (int k = 0; k < 32; k++) {
            float4 a0 = *(const float4*)&sA[k * 132 + rg * 8];
            float4 a1 = *(const float4*)&sA[k * 132 + rg * 8 + 4];
            float b[16];
#pragma unroll
            for (int m = 0; m < 4; m++) {
                float4 bv = *(const float4*)&sB[k * 132 + cg * 4 + 32 * m];
                b[m * 4 + 0] = bv.x; b[m * 4 + 1] = bv.y;
                b[m * 4 + 2] = bv.z; b[m * 4 + 3] = bv.w;
            }
            float a[8] = {a0.x, a0.y, a0.z, a0.w, a1.x, a1.y, a1.z, a1.w};
#pragma unroll
            for (int i = 0; i < 8; i++)
#pragma unroll
                for (int j = 0; j < 16; j++)
                    acc[i][j] = fmaf(a[i], b[j], acc[i][j]);
        }
        __syncthreads();
    }

    float bv16[16];
#pragma unroll
    for (int m = 0; m < 4; m++)
#pragma unroll
        for (int j = 0; j < 4; j++)
            bv16[m * 4 + j] = bias ? bias[cg * 4 + 32 * m + j] : 0.f;
#pragma unroll
    for (int i = 0; i < 8; i++) {
        long r = row0 + rg * 8 + i;
#pragma unroll
        for (int m = 0; m < 4; m++) {
            float4 o;
            o.x = acc[i][m * 4 + 0] + bv16[m * 4 + 0];
            o.y = acc[i][m * 4 + 1] + bv16[m * 4 + 1];
            o.z = acc[i][m * 4 + 2] + bv16[m * 4 + 2];
            o.w = acc[i][m * 4 + 3] + bv16[m * 4 + 3];
            if (leaky) {
                o.x = (o.x >= 0.f) ? o.x : 0.01f * o.x;
                o.y = (o.y >= 0.f) ? o.y : 0.01f * o.y;
                o.z = (o.z >= 0.f) ? o.z : 0.01f * o.z;
                o.w = (o.w >= 0.f) ? o.w : 0.01f * o.w;
            }
            *(float4*)(C + r * 128 + cg * 4 + 32 * m) = o;
        }
    }
    if (statsout) {
        // bias==null && leaky==0 on this path, so stored value == acc
        float s[4] = {0.f, 0.f, 0.f, 0.f}, ss[4] = {0.f, 0.f, 0.f, 0.f};
#pragma unroll
        for (int i = 0; i < 8; i++)
#pragma unroll
            for (int m = 0; m < 4; m++)
#pragma unroll
                for (int j = 0; j < 4; j++) {
                    float v = acc[i][m * 4 + j];
                    s[m] += v; ss[m] += v * v;
                }
#pragma unroll
        for (int m = 0; m < 4; m++) {
            sRed[t * 8 + 2 * m]     = s[m];
            sRed[t * 8 + 2 * m + 1] = ss[m];
        }
        __syncthreads();
        if (t < 8) {
            int g = t >> 1, which = t & 1;
            float a2 = 0.f;
            for (int u = 0; u < 128; u++) a2 += sRed[u * 8 + 2 * g + which];
            statsout[((bidx * 4 + g) * 128 + (int)(blockIdx.x & 127)) * 2 + which] = a2;
        }
    }
}

// ---------------------------------------------------------------------------
// attn: q = gn2(qraw) -> outQ; S = sq_dist(q,q); softmax; min-max -> af
// grid=1024 (2 windows/block), block=256 (128 threads/window, 8x4 tiles).
// sQ XOR-swizzled for conflict-free b128; S aliased into sQ after QK.
// ---------------------------------------------------------------------------
__global__ __launch_bounds__(256, 2) void attn_v2(const float* __restrict__ Qraw,
                                                  const float* __restrict__ stats,
                                                  float* __restrict__ outQ,
                                                  float* __restrict__ outAF)
{
    __shared__ float sQ[2][8192];
    __shared__ float sN[2][64];
    int t = threadIdx.x;
    int wl = t >> 7;               // window half
    int tl = t & 127;
    int w = blockIdx.x * 2 + wl;
    int bidx = w >> 8;
    float muv[4], rsv[4];
#pragma unroll
    for (int g = 0; g < 4; g++) {
        muv[g] = stats[(bidx * 4 + g) * 2];
        rsv[g] = stats[(bidx * 4 + g) * 2 + 1];
    }
    // stage (normalize, write q out, swizzled LDS write)
    {
        int r = tl >> 1, q0 = (tl & 1) * 16;
        int sw = r >> 3;
        const float* src = Qraw + (long)w * 8192 + r * 128 + q0 * 4;
        float* dstG = outQ + (long)w * 8192 + r * 128 + q0 * 4;
#pragma unroll
        for (int q = 0; q < 16; q++) {
            float4 v = *(const float4*)(src + 4 * q);
            int g = (q0 + q) >> 3;
            float mu = muv[g], rs = rsv[g];
            v.x = (v.x - mu) * rs; v.y = (v.y - mu) * rs;
            v.z = (v.z - mu) * rs; v.w = (v.w - mu) * rs;
            *(float4*)(dstG + 4 * q) = v;
            *(float4*)&sQ[wl][r * 128 + 4 * ((q0 + q) ^ sw)] = v;
        }
    }
    __syncthreads();
    if (tl < 64) {
        int r = tl, sw = r >> 3;
        float s = 0.f;
#pragma unroll
        for (int q = 0; q < 32; q++) {
            float4 v = *(const float4*)&sQ[wl][r * 128 + 4 * (q ^ sw)];
            s += v.x * v.x + v.y * v.y + v.z * v.z + v.w * v.w;
        }
        sN[wl][r] = s;
    }
    __syncthreads();
    // QK: rows ty*8+i, cols tx*4+bb
    int ty = tl >> 4, tx = tl & 15;
    float acc[8][4];
#pragma unroll
    for (int i = 0; i < 8; i++)
#pragma unroll
        for (int bb = 0; bb < 4; bb++) acc[i][bb] = 0.f;
    for (int kq = 0; kq < 32; kq++) {
        float4 bf[4];
#pragma unroll
        for (int bb = 0; bb < 4; bb++) {
            int col = tx * 4 + bb;
            bf[bb] = *(const float4*)&sQ[wl][col * 128 + 4 * (kq ^ (col >> 3))];
        }
#pragma unroll
        for (int i = 0; i < 8; i++) {
            int row = ty * 8 + i;
            float4 av = *(const float4*)&sQ[wl][row * 128 + 4 * (kq ^ (row >> 3))];
#pragma unroll
            for (int bb = 0; bb < 4; bb++)
                acc[i][bb] += av.x * bf[bb].x + av.y * bf[bb].y
                            + av.z * bf[bb].z + av.w * bf[bb].w;
        }
    }
    __syncthreads();                 // done reading sQ
    float* sS = &sQ[wl][0];          // alias, stride 65
#pragma unroll
    for (int i = 0; i < 8; i++) {
        int row = ty * 8 + i;
#pragma unroll
        for (int bb = 0; bb < 4; bb++) {
            int col = tx * 4 + bb;
            sS[row * 65 + col] = sN[wl][row] + sN[wl][col] - 2.f * acc[i][bb];
        }
    }
    __syncthreads();
    // epilogue: lane = row, serial over j (no shuffles)
    if (tl < 64) {
        int r = tl;
        float mnS = sS[r * 65];
        for (int j = 1; j < 64; j++) mnS = fminf(mnS, sS[r * 65 + j]);
        float sum = 0.f, pmx = -1.f, pmn = 1e30f;
        for (int j = 0; j < 64; j++) {
            float p = expf(-SCL_F * (sS[r * 65 + j] - mnS));
            sS[r * 65 + j] = p;
            sum += p;
            pmx = fmaxf(pmx, p);
            pmn = fminf(pmn, p);
        }
        float rsum = 1.0f / sum;
        float amn = pmn * rsum, amx = pmx * rsum;
        float dinv = 1.0f / (amx - amn + 1e-8f);
        float* dst = outAF + (long)w * 4096 + r * 64;
        for (int j = 0; j < 64; j += 4) {
            float4 o;
            o.x = (sS[r * 65 + j + 0] * rsum - amn) * dinv;
            o.y = (sS[r * 65 + j + 1] * rsum - amn) * dinv;
            o.z = (sS[r * 65 + j + 2] * rsum - amn) * dinv;
            o.w = (sS[r * 65 + j + 3] * rsum - amn) * dinv;
            *(float4*)(dst + j) = o;
        }
    }
}

// ---------------------------------------------------------------------------
// Per-window clustering, register/readlane rewrite (DS-minimized).
// lane = row q; wave wv owns k = 4kk+wv (registers dk,ak,T[16]).
// Pair sum via min-identity; j<k handled by quad decomposition with
// wave-uniform branches. grid=2048, block=256.
// ---------------------------------------------------------------------------
__global__ __launch_bounds__(256, 4) void cluster_v3(const float* __restrict__ AF,
                                                     const float* __restrict__ GEO,
                                                     float* __restrict__ oCLM,
                                                     float* __restrict__ oCLR,
                                                     float* __restrict__ oCOMP,
                                                     float* __restrict__ oGEO,
                                                     float* __restrict__ oSCM,
                                                     float* __restrict__ wCLMM)
{
    __shared__ float sAF[64 * 65];
    __shared__ float sPart[4 * 64 * 3];
    __shared__ float sCLM[8 * 65];
    int t = threadIdx.x, w = blockIdx.x;
    int wv = t >> 6, lane = t & 63;
    const float* afw = AF + (long)w * 4096;
#pragma unroll
    for (int i = 0; i < 4; i++) {
        int f4 = i * 256 + t;
        float4 v = *(const float4*)(afw + f4 * 4);
        int r = f4 >> 4, c4 = (f4 & 15) * 4;
        float* dst = &sAF[r * 65 + c4];
        dst[0] = fminf(fmaxf(v.x, 1e-5f), 0.99999f);
        dst[1] = fminf(fmaxf(v.y, 1e-5f), 0.99999f);
        dst[2] = fminf(fmaxf(v.z, 1e-5f), 0.99999f);
        dst[3] = fminf(fmaxf(v.w, 1e-5f), 0.99999f);
    }
    // per-lane geo row (lane = element index)
    const float* gp = GEO + ((long)w * 64 + lane) * 6;
    float2 g01 = *(const float2*)(gp);
    float2 g23 = *(const float2*)(gp + 2);
    float2 g45 = *(const float2*)(gp + 4);
    float gD = g01.x, gA = g23.x, gI = g23.y, gX = g45.x, gY = g45.y;
    __syncthreads();

    // ---- phase 1 ----
    const float* afrow = &sAF[lane * 65];
    float dk[16], ak[16], T[16];
    float v0 = 0.f, v1 = 0.f;
#pragma unroll
    for (int kk = 0; kk < 16; kk++) {
        int kc = kk * 4 + wv;
        float afk = afrow[kc];
        float d = afk * rlane(gD, kc);
        float a = afk * rlane(gA, kc);
        dk[kk] = d; ak[kk] = a; T[kk] = 0.f;
        float m = d * a;
        float dx = gX - rlane(gX, kc), dy = gY - rlane(gY, kc);
        v0 += d * rlane(gI, kc) + m * (dx * dx + dy * dy);
        v1 += m * a;
    }
    for (int jq = 0; jq < 16; jq++) {
        float dj[4], aj[4];
#pragma unroll
        for (int jr = 0; jr < 4; jr++) {
            int j = jq * 4 + jr;
            float afj = afrow[j];
            dj[jr] = afj * rlane(gD, j);
            aj[jr] = afj * rlane(gA, j);
        }
#pragma unroll
        for (int kk = 0; kk < 16; kk++) {
            if (kk > jq) {
#pragma unroll
                for (int jr = 0; jr < 4; jr++)
                    T[kk] = fmaf(aj[jr], fminf(dj[jr], dk[kk]), T[kk]);
            } else if (kk == jq) {
                if (0 < wv) T[kk] = fmaf(aj[0], fminf(dj[0], dk[kk]), T[kk]);
                if (1 < wv) T[kk] = fmaf(aj[1], fminf(dj[1], dk[kk]), T[kk]);
                if (2 < wv) T[kk] = fmaf(aj[2], fminf(dj[2], dk[kk]), T[kk]);
            }
        }
    }
    float S = 0.f;
#pragma unroll
    for (int kk = 0; kk < 16; kk++) S = fmaf(ak[kk], T[kk], S);
    {
        float* p = &sPart[(wv * 64 + lane) * 3];
        p[0] = v0; p[1] = v1; p[2] = S;
    }
    __syncthreads();

    // ---- combine + greedy selection (wave 0) ----
    if (t < 64) {
        int k = lane;
        float c0 = 0.f, c1 = 0.f, c2 = 0.f;
#pragma unroll
        for (int u = 0; u < 4; u++) {
            const float* p = &sPart[(u * 64 + k) * 3];
            c0 += p[0]; c1 += p[1]; c2 += p[2];
        }
        float compk = ((c1 + 2.f * c2) / TWO_PI_F) / c0;
        float sc = 1.0f;
        for (int c = 0; c < 7; c++) {
            float score = compk * sc;
            float mx = score;
            for (int off = 1; off < 64; off <<= 1) mx = fmaxf(mx, __shfl_xor(mx, off));
            unsigned long long bl = __ballot(score == mx);
            int idx = __ffsll(bl) - 1;
            float rowk = sAF[idx * 65 + k];
            float clm = sc * rowk;
            sCLM[c * 65 + k] = clm;
            oCLM[(long)w * 512 + c * 64 + k] = clm;
            if (k == 0) oCLR[(long)w * 7 + c] = (float)idx;
            sc *= (1.0f - rowk);
        }
        sCLM[7 * 65 + k] = sc;
        oCLM[(long)w * 512 + 448 + k] = sc;
        oSCM[(long)w * 64 + k] = sc;
    }
    __syncthreads();

    // ---- phase 3: cluster aggregates + second compactness (2 clusters/wave) ----
    {
        int k = lane;
        for (int cc = 0; cc < 2; cc++) {
            int c = wv + cc * 4;
            float clm = sCLM[c * 65 + k];
            float cd = clm * gD, ca = clm * gA;
            float cm = cd * ca;
            float T3 = 0.f;
            for (int j = 0; j < 64; j++)
                T3 = fmaf(rlane(ca, j), fminf(rlane(cd, j), cd), T3);
            float r0 = cm, r1 = ca, r2c = cm * gX, r3 = cm * gY, r4 = clm;
            float r5 = cm * ca;
            float r6 = ca * T3 - ca * ca * cd;   // 2*S contribution (self removed)
            for (int off = 1; off < 64; off <<= 1) {
                r0 += __shfl_xor(r0, off); r1 += __shfl_xor(r1, off);
                r2c += __shfl_xor(r2c, off); r3 += __shfl_xor(r3, off);
                r4 += __shfl_xor(r4, off); r5 += __shfl_xor(r5, off);
                r6 += __shfl_xor(r6, off);
            }
            float mass = r0, area = r1;
            float qx = r2c / (mass + 1e-8f), qy = r3 / (mass + 1e-8f);
            wCLMM[(long)w * 512 + c * 64 + k] = clm / (r4 + 1e-8f);
            float dx = qx - gX, dy = qy - gY;
            float w0v = cd * gI + cm * (dx * dx + dy * dy);
            for (int off = 1; off < 64; off <<= 1) w0v += __shfl_xor(w0v, off);
            if (k == 0) {
                oCOMP[(long)w * 8 + c] = ((r5 + r6) / TWO_PI_F) / w0v;
                float* og = oGEO + (long)w * 48 + c * 6;
                og[0] = mass / (area + 1e-8f); og[1] = mass; og[2] = area;
                og[3] = w0v; og[4] = qx; og[5] = qy;
            }
        }
    }
}

// ---------------------------------------------------------------------------
// cl_f = t1*sigma + sc*(mu+b2) + bfc + u@W2 + t1@Wvf   (Wvf = Wv@Wfc)
//   u = mm@h1, t1 = mm@_fn. readlane-based GEMVs. grid=2048, block=256.
// v3: NO LDS staging of h1/in_f — stage-1 streams straight from global
// (each (j,ch) element is consumed exactly once; per-wave reads are 256B
// coalesced and L2/LLC-resident). LDS shrinks 74KB -> ~12KB (only the
// cross-wave sU/sT/sP exchange buffers), lifting occupancy 2 -> ~4 blk/CU
// and killing the 4-way bank conflicts of the old staging stores.
// Waves: 0/1 -> u (ch half 0/1); 2/3 -> t1. Stage2: 0/1 -> W2; 2/3 -> Wvf.
// ---------------------------------------------------------------------------
__global__ __launch_bounds__(256, 4) void final_v3(const float* __restrict__ inF,
                                                   const float* __restrict__ H1,
                                                   const float* __restrict__ CLMM,
                                                   const float* __restrict__ stats1,
                                                   const float* __restrict__ W2,
                                                   const float* __restrict__ b2,
                                                   const float* __restrict__ Wvf,
                                                   const float* __restrict__ bfc,
                                                   float* __restrict__ oCLF)
{
    __shared__ float sU[8 * 129];
    __shared__ float sT[8 * 129];
    __shared__ float sP[8 * 129];
    int t = threadIdx.x, w = blockIdx.x;
    int bidx = w >> 8;
    int wv = t >> 6, lane = t & 63;
    int ch = lane + 64 * (wv & 1);

    float mmL[8];
#pragma unroll
    for (int c = 0; c < 8; c++)
        mmL[c] = CLMM[(long)w * 512 + c * 64 + lane];

    float mu = stats1[(bidx * 4 + (ch >> 5)) * 2];
    float rs = stats1[(bidx * 4 + (ch >> 5)) * 2 + 1];

    // ---- stage 1: K=64 GEMVs straight from global ----
    float acc1[8];
#pragma unroll
    for (int c = 0; c < 8; c++) acc1[c] = 0.f;
    if (wv < 2) {
        const float* src = H1 + (long)w * 8192 + ch;
#pragma unroll 4
        for (int j = 0; j < 64; j++) {
            float f = src[j * 128];
#pragma unroll
            for (int c = 0; c < 8; c++)
                acc1[c] = fmaf(rlane(mmL[c], j), f, acc1[c]);
        }
#pragma unroll
        for (int c = 0; c < 8; c++) sU[c * 129 + ch] = acc1[c];
    } else {
        const float* src = inF + (long)w * 8192 + ch;
#pragma unroll 4
        for (int j = 0; j < 64; j++) {
            float f = (src[j * 128] - mu) * rs;
#pragma unroll
            for (int c = 0; c < 8; c++)
                acc1[c] = fmaf(rlane(mmL[c], j), f, acc1[c]);
        }
#pragma unroll
        for (int c = 0; c < 8; c++) sT[c * 129 + ch] = acc1[c];
    }
    __syncthreads();
    // ---- stage 2: K=128 GEMVs with global weights ----
    float xL0[8], xL1[8];
    {
        const float* s2 = (wv < 2) ? sU : sT;
#pragma unroll
        for (int c = 0; c < 8; c++) {
            xL0[c] = s2[c * 129 + lane];
            xL1[c] = s2[c * 129 + 64 + lane];
        }
    }
    const float* Wm = (wv < 2) ? W2 : Wvf;
    float acc2[8];
#pragma unroll
    for (int c = 0; c < 8; c++) acc2[c] = 0.f;
#pragma unroll 2
    for (int k = 0; k < 64; k++) {
        float wk = Wm[k * 128 + ch];
#pragma unroll
        for (int c = 0; c < 8; c++)
            acc2[c] = fmaf(rlane(xL0[c], k), wk, acc2[c]);
    }
#pragma unroll 2
    for (int k = 0; k < 64; k++) {
        float wk = Wm[(k + 64) * 128 + ch];
#pragma unroll
        for (int c = 0; c < 8; c++)
            acc2[c] = fmaf(rlane(xL1[c], k), wk, acc2[c]);
    }
    if (wv >= 2) {
        // + t1 * sigma  (t1[c][ch] is this lane's own value)
        float sig = 1.0f / rs;
#pragma unroll
        for (int c = 0; c < 8; c++) {
            float t1ch = (wv & 1) ? xL1[c] : xL0[c];
            acc2[c] = fmaf(t1ch, sig, acc2[c]);
        }
#pragma unroll
        for (int c = 0; c < 8; c++) sP[c * 129 + ch] = acc2[c];
    }
    __syncthreads();
    if (wv < 2) {
        float scv[8];
#pragma unroll
        for (int c = 0; c < 8; c++) {
            float s = mmL[c];
            for (int off = 1; off < 64; off <<= 1) s += __shfl_xor(s, off);
            scv[c] = s;
        }
        float mub = mu + b2[ch];
        float bfv = bfc[ch];
#pragma unroll
        for (int c = 0; c < 8; c++) {
            float o = acc2[c] + sP[c * 129 + ch] + scv[c] * mub + bfv;
            oCLF[(long)w * 1024 + c * 128 + ch] = o;
        }
    }
}

// ---------------------------------------------------------------------------
extern "C" void kernel_launch(void* const* d_in, const int* in_sizes, int n_in,
                              void* d_out, int out_size, void* d_ws, size_t ws_size,
                              hipStream_t stream)
{
    (void)in_sizes; (void)n_in; (void)out_size; (void)ws_size;
    const float* in_f   = (const float*)d_in[0];
    const float* in_geo = (const float*)d_in[1];
    const float* W1  = (const float*)d_in[2];
    const float* b1  = (const float*)d_in[3];
    const float* W2  = (const float*)d_in[4];
    const float* b2  = (const float*)d_in[5];
    const float* Wfc = (const float*)d_in[6];
    const float* bfc = (const float*)d_in[7];
    const float* Wq  = (const float*)d_in[8];
    const float* Wv  = (const float*)d_in[9];
    float* out = (float*)d_out;
    float* ws  = (float*)d_ws;

    // workspace (floats)
    float* qh     = ws;                    // 16,777,216 (qraw then h1)
    float* clmm   = ws + 16777216;         //  1,048,576
    float* stats1 = ws + 17825792;         //  64
    float* stats2 = ws + 17825856;         //  64
    float* wvf    = ws + 17825920;         //  16,384
    float* part   = ws + 17842304;         //  8,192

    // output layout (floats)
    float* o_clf  = out;                   // (8,256,8,128)
    float* o_clm  = out + 2097152;         // (8,256,8,64)
    float* o_geo  = out + 3145728;         // (8,256,8,6)
    float* o_clr  = out + 3244032;         // (8,256,7,1)
    float* o_comp = out + 3258368;         // (8,256,8,1)
    float* o_af   = out + 3274752;         // (8,256,64,64)
    float* o_scm  = out + 11663360;        // (8,256,1,64)
    float* o_q    = out + 11794432;        // (8,256,64,128)

    gn_partial_k<<<dim3(64, 32), 256, 0, stream>>>(in_f, part);
    gn_final_k<<<32, 64, 0, stream>>>(part, stats1, 64);
    wvf_prep_k<<<32, 256, 0, stream>>>(Wv, Wfc, wvf);
    // qraw = gn1(in_f) @ Wq, fused stats2 partials
    gemm128_v2<<<1024, 128, 0, stream>>>(in_f, Wq, nullptr, stats1, qh, 0, part);
    gn_final_k<<<32, 64, 0, stream>>>(part, stats2, 128);
    attn_v2<<<1024, 256, 0, stream>>>(qh, stats2, o_q, o_af);
    // h1 = leaky(gn1(in_f) @ W1 + b1) (reuses qraw buffer)
    gemm128_v2<<<1024, 128, 0, stream>>>(in_f, W1, b1, stats1, qh, 1, nullptr);
    cluster_v3<<<2048, 256, 0, stream>>>(o_af, in_geo, o_clm, o_clr, o_comp, o_geo,
                                         o_scm, clmm);
    final_v3<<<2048, 256, 0, stream>>>(in_f, qh, clmm, stats1, W2, b2, wvf, bfc, o_clf);
}

// Round 2
// 482.187 us; speedup vs baseline: 1.0208x; 1.0062x over previous
//
#include <hip/hip_runtime.h>

#define TWO_PI_F 6.28318530717958647692f
#define SCL_F    0.02209708691207961f   // TEMP/SCALE/sqrt(128)

__device__ __forceinline__ float rlane(float v, int l) {
    return __uint_as_float((unsigned)__builtin_amdgcn_readlane((int)__float_as_uint(v), l));
}

// ---------------------------------------------------------------------------
// Group-norm partial stats for in_f: per (b,g) over 16384 rows x 32 ch.
// grid=(64,32), block=256
// ---------------------------------------------------------------------------
__global__ __launch_bounds__(256) void gn_partial_k(const float* __restrict__ X,
                                                    float* __restrict__ partials)
{
    int t = threadIdx.x;
    int chunk = blockIdx.x;
    int grp = blockIdx.y;          // b*4+g
    int b = grp >> 2, g = grp & 3;
    const float* base = X + ((long)b * 16384 + (long)chunk * 256) * 128 + g * 32;
    float s = 0.f, ss = 0.f;
#pragma unroll
    for (int i = 0; i < 8; i++) {
        int rl_ = i * 32 + (t >> 3);
        int c4 = (t & 7) * 4;
        float4 v = *(const float4*)(base + (long)rl_ * 128 + c4);
        s  += v.x + v.y + v.z + v.w;
        ss += v.x * v.x + v.y * v.y + v.z * v.z + v.w * v.w;
    }
    __shared__ float r0[256], r1[256];
    r0[t] = s; r1[t] = ss;
    __syncthreads();
    for (int off = 128; off > 0; off >>= 1) {
        if (t < off) { r0[t] += r0[t + off]; r1[t] += r1[t + off]; }
        __syncthreads();
    }
    if (t == 0) {
        partials[(grp * 64 + chunk) * 2]     = r0[0];
        partials[(grp * 64 + chunk) * 2 + 1] = r1[0];
    }
}

// grid=32, block=64; nblk partials per group
__global__ void gn_final_k(const float* __restrict__ partials, float* __restrict__ stats,
                           int nblk)
{
    int grp = blockIdx.x, t = threadIdx.x;
    float s = 0.f, ss = 0.f;
    for (int i = t; i < nblk; i += 64) {
        s  += partials[(grp * nblk + i) * 2];
        ss += partials[(grp * nblk + i) * 2 + 1];
    }
    for (int off = 1; off < 64; off <<= 1) { s += __shfl_xor(s, off); ss += __shfl_xor(ss, off); }
    if (t == 0) {
        const float N = 524288.0f;
        float mu = s / N;
        float var = ss / N - mu * mu;
        stats[grp * 2]     = mu;
        stats[grp * 2 + 1] = 1.0f / sqrtf(var + 0.001f);
    }
}

// ---------------------------------------------------------------------------
// Wvf = Wv @ Wfc  (128x128). grid=32 blocks x 256 threads (4 rows/block).
// ---------------------------------------------------------------------------
__global__ __launch_bounds__(256) void wvf_prep_k(const float* __restrict__ Wv,
                                                  const float* __restrict__ Wfc,
                                                  float* __restrict__ out)
{
    int t = threadIdx.x;
    int rr = t >> 6, cl = t & 63;
    int r = blockIdx.x * 4 + rr;
    float a0 = 0.f, a1 = 0.f;
    for (int k = 0; k < 128; k++) {
        float wv = Wv[r * 128 + k];
        a0 = fmaf(wv, Wfc[k * 128 + cl], a0);
        a1 = fmaf(wv, Wfc[k * 128 + 64 + cl], a1);
    }
    out[r * 128 + cl] = a0;
    out[r * 128 + 64 + cl] = a1;
}

// ---------------------------------------------------------------------------
// Fused dual GEMM: A = gn1(in_f) tile staged ONCE; waves 0/1 compute
// C1 = leaky(A@W1 + b1) -> h1; waves 2/3 compute C2 = A@Wq -> qraw (+ fused
// stats2 partials from acc). grid=1024 (128 rows/block), block=256
// (128 threads per weight matrix, per-thread 8x16 tile as in gemm128_v2).
// Threads 0-127 stage A (transposed+normalized); threads 128-255 stage both
// B tiles. LDS ~54.8KB -> 2 blocks/CU (8 waves/CU), same as the split version,
// but in_f is read+normalized+staged once instead of twice.
// ---------------------------------------------------------------------------
__global__ __launch_bounds__(256, 2) void gemm256_fused(const float* __restrict__ X,
                                                        const float* __restrict__ W1,
                                                        const float* __restrict__ b1,
                                                        const float* __restrict__ Wq,
                                                        const float* __restrict__ stats,
                                                        float* __restrict__ C1,
                                                        float* __restrict__ C2,
                                                        float* __restrict__ statsout)
{
    __shared__ float sA[32 * 132];
    __shared__ float sB[2][32 * 132];
    __shared__ float sRed[128 * 8];
    int t = threadIdx.x;
    int hw = t >> 7, ht = t & 127;   // hw: 0 -> W1 path, 1 -> Wq path
    long row0 = (long)blockIdx.x * 128;
    int bidx = (int)(row0 >> 14);

    float muv[4], rsv[4];
#pragma unroll
    for (int g = 0; g < 4; g++) {
        muv[g] = stats[(bidx * 4 + g) * 2];
        rsv[g] = stats[(bidx * 4 + g) * 2 + 1];
    }
    int rg = ht >> 3, cg = ht & 7;
    float acc[8][16];
#pragma unroll
    for (int i = 0; i < 8; i++)
#pragma unroll
        for (int j = 0; j < 16; j++) acc[i][j] = 0.f;

    const float* xs = X + (row0 + ht) * 128;
    int kb = ht >> 2, c0 = (ht & 3) * 32;

    for (int kt = 0; kt < 4; kt++) {
        if (hw == 0) {
            // stage A transposed + normalized (k-range [32kt,32kt+32) == group kt)
            float mu = muv[kt], rs = rsv[kt];
            const float* asrc = xs + kt * 32;
#pragma unroll
            for (int q = 0; q < 8; q++) {
                float4 v = *(const float4*)(asrc + 4 * q);
                sA[(4 * q + 0) * 132 + ht] = (v.x - mu) * rs;
                sA[(4 * q + 1) * 132 + ht] = (v.y - mu) * rs;
                sA[(4 * q + 2) * 132 + ht] = (v.z - mu) * rs;
                sA[(4 * q + 3) * 132 + ht] = (v.w - mu) * rs;
            }
        } else {
            // stage both B tiles
            const float* bsrc1 = W1 + (long)(kt * 32 + kb) * 128 + c0;
            const float* bsrc2 = Wq + (long)(kt * 32 + kb) * 128 + c0;
#pragma unroll
            for (int q = 0; q < 8; q++)
                *(float4*)&sB[0][kb * 132 + c0 + 4 * q] = *(const float4*)(bsrc1 + 4 * q);
#pragma unroll
            for (int q = 0; q < 8; q++)
                *(float4*)&sB[1][kb * 132 + c0 + 4 * q] = *(const float4*)(bsrc2 + 4 * q);
        }
        __syncthreads();
        const float* sBh = sB[hw];
#pragma unroll 4
        for (int k = 0; k < 32; k++) {
            float4 a0 = *(const float4*)&sA[k * 132 + rg * 8];
            float4 a1 = *(const float4*)&sA[k * 132 + rg * 8 + 4];
            float b[16];
#pragma unroll
            for (int m = 0; m < 4; m++) {
                float4 bv = *(const float4*)&sBh[k * 132 + cg * 4 + 32 * m];
                b[m * 4 + 0] = bv.x; b[m * 4 + 1] = bv.y;
                b[m * 4 + 2] = bv.z; b[m * 4 + 3] = bv.w;
            }
            float a[8] = {a0.x, a0.y, a0.z, a0.w, a1.x, a1.y, a1.z, a1.w};
#pragma unroll
            for (int i = 0; i < 8; i++)
#pragma unroll
                for (int j = 0; j < 16; j++)
                    acc[i][j] = fmaf(a[i], b[j], acc[i][j]);
        }
        __syncthreads();
    }

    float bv16[16];
#pragma unroll
    for (int m = 0; m < 4; m++)
#pragma unroll
        for (int j = 0; j < 4; j++)
            bv16[m * 4 + j] = (hw == 0) ? b1[cg * 4 + 32 * m + j] : 0.f;
    float* C = hw ? C2 : C1;
#pragma unroll
    for (int i = 0; i < 8; i++) {
        long r = row0 + rg * 8 + i;
#pragma unroll
        for (int m = 0; m < 4; m++) {
            float4 o;
            o.x = acc[i][m * 4 + 0] + bv16[m * 4 + 0];
            o.y = acc[i][m * 4 + 1] + bv16[m * 4 + 1];
            o.z = acc[i][m * 4 + 2] + bv16[m * 4 + 2];
            o.w = acc[i][m * 4 + 3] + bv16[m * 4 + 3];
            if (hw == 0) {
                o.x = (o.x >= 0.f) ? o.x : 0.01f * o.x;
                o.y = (o.y >= 0.f) ? o.y : 0.01f * o.y;
                o.z = (o.z >= 0.f) ? o.z : 0.01f * o.z;
                o.w = (o.w >= 0.f) ? o.w : 0.01f * o.w;
            }
            *(float4*)(C + r * 128 + cg * 4 + 32 * m) = o;
        }
    }
    // fused gn2 partial stats from the Wq half (stored value == acc there)
    if (hw == 1) {
        float s[4] = {0.f, 0.f, 0.f, 0.f}, ss[4] = {0.f, 0.f, 0.f, 0.f};
#pragma unroll
        for (int i = 0; i < 8; i++)
#pragma unroll
            for (int m = 0; m < 4; m++)
#pragma unroll
                for (int j = 0; j < 4; j++) {
                    float v = acc[i][m * 4 + j];
                    s[m] += v; ss[m] += v * v;
                }
#pragma unroll
        for (int m = 0; m < 4; m++) {
            sRed[ht * 8 + 2 * m]     = s[m];
            sRed[ht * 8 + 2 * m + 1] = ss[m];
        }
    }
    __syncthreads();
    if (hw == 1 && ht < 8) {
        int g = ht >> 1, which = ht & 1;
        float a2 = 0.f;
        for (int u = 0; u < 128; u++) a2 += sRed[u * 8 + 2 * g + which];
        statsout[((bidx * 4 + g) * 128 + (int)(blockIdx.x & 127)) * 2 + which] = a2;
    }
}

// ---------------------------------------------------------------------------
// attn: q = gn2(qraw) -> outQ; S = sq_dist(q,q); softmax; min-max -> af
// grid=1024 (2 windows/block), block=256 (128 threads/window, 8x4 tiles).
// sQ XOR-swizzled for conflict-free b128; S aliased into sQ after QK.
// Safe to run IN PLACE (Qraw == outQ): each float4 is read then written by
// the same thread.
// ---------------------------------------------------------------------------
__global__ __launch_bounds__(256, 2) void attn_v2(const float* __restrict__ Qraw,
                                                  const float* __restrict__ stats,
                                                  float* __restrict__ outQ,
                                                  float* __restrict__ outAF)
{
    __shared__ float sQ[2][8192];
    __shared__ float sN[2][64];
    int t = threadIdx.x;
    int wl = t >> 7;               // window half
    int tl = t & 127;
    int w = blockIdx.x * 2 + wl;
    int bidx = w >> 8;
    float muv[4], rsv[4];
#pragma unroll
    for (int g = 0; g < 4; g++) {
        muv[g] = stats[(bidx * 4 + g) * 2];
        rsv[g] = stats[(bidx * 4 + g) * 2 + 1];
    }
    // stage (normalize, write q out, swizzled LDS write)
    {
        int r = tl >> 1, q0 = (tl & 1) * 16;
        int sw = r >> 3;
        const float* src = Qraw + (long)w * 8192 + r * 128 + q0 * 4;
        float* dstG = outQ + (long)w * 8192 + r * 128 + q0 * 4;
#pragma unroll
        for (int q = 0; q < 16; q++) {
            float4 v = *(const float4*)(src + 4 * q);
            int g = (q0 + q) >> 3;
            float mu = muv[g], rs = rsv[g];
            v.x = (v.x - mu) * rs; v.y = (v.y - mu) * rs;
            v.z = (v.z - mu) * rs; v.w = (v.w - mu) * rs;
            *(float4*)(dstG + 4 * q) = v;
            *(float4*)&sQ[wl][r * 128 + 4 * ((q0 + q) ^ sw)] = v;
        }
    }
    __syncthreads();
    if (tl < 64) {
        int r = tl, sw = r >> 3;
        float s = 0.f;
#pragma unroll
        for (int q = 0; q < 32; q++) {
            float4 v = *(const float4*)&sQ[wl][r * 128 + 4 * (q ^ sw)];
            s += v.x * v.x + v.y * v.y + v.z * v.z + v.w * v.w;
        }
        sN[wl][r] = s;
    }
    __syncthreads();
    // QK: rows ty*8+i, cols tx*4+bb
    int ty = tl >> 4, tx = tl & 15;
    float acc[8][4];
#pragma unroll
    for (int i = 0; i < 8; i++)
#pragma unroll
        for (int bb = 0; bb < 4; bb++) acc[i][bb] = 0.f;
    for (int kq = 0; kq < 32; kq++) {
        float4 bf[4];
#pragma unroll
        for (int bb = 0; bb < 4; bb++) {
            int col = tx * 4 + bb;
            bf[bb] = *(const float4*)&sQ[wl][col * 128 + 4 * (kq ^ (col >> 3))];
        }
#pragma unroll
        for (int i = 0; i < 8; i++) {
            int row = ty * 8 + i;
            float4 av = *(const float4*)&sQ[wl][row * 128 + 4 * (kq ^ (row >> 3))];
#pragma unroll
            for (int bb = 0; bb < 4; bb++)
                acc[i][bb] += av.x * bf[bb].x + av.y * bf[bb].y
                            + av.z * bf[bb].z + av.w * bf[bb].w;
        }
    }
    __syncthreads();                 // done reading sQ
    float* sS = &sQ[wl][0];          // alias, stride 65
#pragma unroll
    for (int i = 0; i < 8; i++) {
        int row = ty * 8 + i;
#pragma unroll
        for (int bb = 0; bb < 4; bb++) {
            int col = tx * 4 + bb;
            sS[row * 65 + col] = sN[wl][row] + sN[wl][col] - 2.f * acc[i][bb];
        }
    }
    __syncthreads();
    // epilogue: lane = row, serial over j (no shuffles)
    if (tl < 64) {
        int r = tl;
        float mnS = sS[r * 65];
        for (int j = 1; j < 64; j++) mnS = fminf(mnS, sS[r * 65 + j]);
        float sum = 0.f, pmx = -1.f, pmn = 1e30f;
        for (int j = 0; j < 64; j++) {
            float p = expf(-SCL_F * (sS[r * 65 + j] - mnS));
            sS[r * 65 + j] = p;
            sum += p;
            pmx = fmaxf(pmx, p);
            pmn = fminf(pmn, p);
        }
        float rsum = 1.0f / sum;
        float amn = pmn * rsum, amx = pmx * rsum;
        float dinv = 1.0f / (amx - amn + 1e-8f);
        float* dst = outAF + (long)w * 4096 + r * 64;
        for (int j = 0; j < 64; j += 4) {
            float4 o;
            o.x = (sS[r * 65 + j + 0] * rsum - amn) * dinv;
            o.y = (sS[r * 65 + j + 1] * rsum - amn) * dinv;
            o.z = (sS[r * 65 + j + 2] * rsum - amn) * dinv;
            o.w = (sS[r * 65 + j + 3] * rsum - amn) * dinv;
            *(float4*)(dst + j) = o;
        }
    }
}

// ---------------------------------------------------------------------------
// Per-window clustering, register/readlane rewrite (DS-minimized).
// lane = row q; wave wv owns k = 4kk+wv (registers dk,ak,T[16]).
// Pair sum via min-identity; j<k handled by quad decomposition with
// wave-uniform branches. grid=2048, block=256.
// ---------------------------------------------------------------------------
__global__ __launch_bounds__(256, 4) void cluster_v3(const float* __restrict__ AF,
                                                     const float* __restrict__ GEO,
                                                     float* __restrict__ oCLM,
                                                     float* __restrict__ oCLR,
                                                     float* __restrict__ oCOMP,
                                                     float* __restrict__ oGEO,
                                                     float* __restrict__ oSCM,
                                                     float* __restrict__ wCLMM)
{
    __shared__ float sAF[64 * 65];
    __shared__ float sPart[4 * 64 * 3];
    __shared__ float sCLM[8 * 65];
    int t = threadIdx.x, w = blockIdx.x;
    int wv = t >> 6, lane = t & 63;
    const float* afw = AF + (long)w * 4096;
#pragma unroll
    for (int i = 0; i < 4; i++) {
        int f4 = i * 256 + t;
        float4 v = *(const float4*)(afw + f4 * 4);
        int r = f4 >> 4, c4 = (f4 & 15) * 4;
        float* dst = &sAF[r * 65 + c4];
        dst[0] = fminf(fmaxf(v.x, 1e-5f), 0.99999f);
        dst[1] = fminf(fmaxf(v.y, 1e-5f), 0.99999f);
        dst[2] = fminf(fmaxf(v.z, 1e-5f), 0.99999f);
        dst[3] = fminf(fmaxf(v.w, 1e-5f), 0.99999f);
    }
    // per-lane geo row (lane = element index)
    const float* gp = GEO + ((long)w * 64 + lane) * 6;
    float2 g01 = *(const float2*)(gp);
    float2 g23 = *(const float2*)(gp + 2);
    float2 g45 = *(const float2*)(gp + 4);
    float gD = g01.x, gA = g23.x, gI = g23.y, gX = g45.x, gY = g45.y;
    __syncthreads();

    // ---- phase 1 ----
    const float* afrow = &sAF[lane * 65];
    float dk[16], ak[16], T[16];
    float v0 = 0.f, v1 = 0.f;
#pragma unroll
    for (int kk = 0; kk < 16; kk++) {
        int kc = kk * 4 + wv;
        float afk = afrow[kc];
        float d = afk * rlane(gD, kc);
        float a = afk * rlane(gA, kc);
        dk[kk] = d; ak[kk] = a; T[kk] = 0.f;
        float m = d * a;
        float dx = gX - rlane(gX, kc), dy = gY - rlane(gY, kc);
        v0 += d * rlane(gI, kc) + m * (dx * dx + dy * dy);
        v1 += m * a;
    }
    for (int jq = 0; jq < 16; jq++) {
        float dj[4], aj[4];
#pragma unroll
        for (int jr = 0; jr < 4; jr++) {
            int j = jq * 4 + jr;
            float afj = afrow[j];
            dj[jr] = afj * rlane(gD, j);
            aj[jr] = afj * rlane(gA, j);
        }
#pragma unroll
        for (int kk = 0; kk < 16; kk++) {
            if (kk > jq) {
#pragma unroll
                for (int jr = 0; jr < 4; jr++)
                    T[kk] = fmaf(aj[jr], fminf(dj[jr], dk[kk]), T[kk]);
            } else if (kk == jq) {
                if (0 < wv) T[kk] = fmaf(aj[0], fminf(dj[0], dk[kk]), T[kk]);
                if (1 < wv) T[kk] = fmaf(aj[1], fminf(dj[1], dk[kk]), T[kk]);
                if (2 < wv) T[kk] = fmaf(aj[2], fminf(dj[2], dk[kk]), T[kk]);
            }
        }
    }
    float S = 0.f;
#pragma unroll
    for (int kk = 0; kk < 16; kk++) S = fmaf(ak[kk], T[kk], S);
    {
        float* p = &sPart[(wv * 64 + lane) * 3];
        p[0] = v0; p[1] = v1; p[2] = S;
    }
    __syncthreads();

    // ---- combine + greedy selection (wave 0) ----
    if (t < 64) {
        int k = lane;
        float c0 = 0.f, c1 = 0.f, c2 = 0.f;
#pragma unroll
        for (int u = 0; u < 4; u++) {
            const float* p = &sPart[(u * 64 + k) * 3];
            c0 += p[0]; c1 += p[1]; c2 += p[2];
        }
        float compk = ((c1 + 2.f * c2) / TWO_PI_F) / c0;
        float sc = 1.0f;
        for (int c = 0; c < 7; c++) {
            float score = compk * sc;
            float mx = score;
            for (int off = 1; off < 64; off <<= 1) mx = fmaxf(mx, __shfl_xor(mx, off));
            unsigned long long bl = __ballot(score == mx);
            int idx = __ffsll(bl) - 1;
            float rowk = sAF[idx * 65 + k];
            float clm = sc * rowk;
            sCLM[c * 65 + k] = clm;
            oCLM[(long)w * 512 + c * 64 + k] = clm;
            if (k == 0) oCLR[(long)w * 7 + c] = (float)idx;
            sc *= (1.0f - rowk);
        }
        sCLM[7 * 65 + k] = sc;
        oCLM[(long)w * 512 + 448 + k] = sc;
        oSCM[(long)w * 64 + k] = sc;
    }
    __syncthreads();

    // ---- phase 3: cluster aggregates + second compactness (2 clusters/wave) ----
    {
        int k = lane;
        for (int cc = 0; cc < 2; cc++) {
            int c = wv + cc * 4;
            float clm = sCLM[c * 65 + k];
            float cd = clm * gD, ca = clm * gA;
            float cm = cd * ca;
            float T3 = 0.f;
            for (int j = 0; j < 64; j++)
                T3 = fmaf(rlane(ca, j), fminf(rlane(cd, j), cd), T3);
            float r0 = cm, r1 = ca, r2c = cm * gX, r3 = cm * gY, r4 = clm;
            float r5 = cm * ca;
            float r6 = ca * T3 - ca * ca * cd;   // 2*S contribution (self removed)
            for (int off = 1; off < 64; off <<= 1) {
                r0 += __shfl_xor(r0, off); r1 += __shfl_xor(r1, off);
                r2c += __shfl_xor(r2c, off); r3 += __shfl_xor(r3, off);
                r4 += __shfl_xor(r4, off); r5 += __shfl_xor(r5, off);
                r6 += __shfl_xor(r6, off);
            }
            float mass = r0, area = r1;
            float qx = r2c / (mass + 1e-8f), qy = r3 / (mass + 1e-8f);
            wCLMM[(long)w * 512 + c * 64 + k] = clm / (r4 + 1e-8f);
            float dx = qx - gX, dy = qy - gY;
            float w0v = cd * gI + cm * (dx * dx + dy * dy);
            for (int off = 1; off < 64; off <<= 1) w0v += __shfl_xor(w0v, off);
            if (k == 0) {
                oCOMP[(long)w * 8 + c] = ((r5 + r6) / TWO_PI_F) / w0v;
                float* og = oGEO + (long)w * 48 + c * 6;
                og[0] = mass / (area + 1e-8f); og[1] = mass; og[2] = area;
                og[3] = w0v; og[4] = qx; og[5] = qy;
            }
        }
    }
}

// ---------------------------------------------------------------------------
// cl_f = t1*sigma + sc*(mu+b2) + bfc + u@W2 + t1@Wvf   (Wvf = Wv@Wfc)
//   u = mm@h1, t1 = mm@_fn. readlane-based GEMVs. grid=2048, block=256.
// v3: NO LDS staging of h1/in_f — stage-1 streams straight from global.
// Waves: 0/1 -> u (ch half 0/1); 2/3 -> t1. Stage2: 0/1 -> W2; 2/3 -> Wvf.
// ---------------------------------------------------------------------------
__global__ __launch_bounds__(256, 4) void final_v3(const float* __restrict__ inF,
                                                   const float* __restrict__ H1,
                                                   const float* __restrict__ CLMM,
                                                   const float* __restrict__ stats1,
                                                   const float* __restrict__ W2,
                                                   const float* __restrict__ b2,
                                                   const float* __restrict__ Wvf,
                                                   const float* __restrict__ bfc,
                                                   float* __restrict__ oCLF)
{
    __shared__ float sU[8 * 129];
    __shared__ float sT[8 * 129];
    __shared__ float sP[8 * 129];
    int t = threadIdx.x, w = blockIdx.x;
    int bidx = w >> 8;
    int wv = t >> 6, lane = t & 63;
    int ch = lane + 64 * (wv & 1);

    float mmL[8];
#pragma unroll
    for (int c = 0; c < 8; c++)
        mmL[c] = CLMM[(long)w * 512 + c * 64 + lane];

    float mu = stats1[(bidx * 4 + (ch >> 5)) * 2];
    float rs = stats1[(bidx * 4 + (ch >> 5)) * 2 + 1];

    // ---- stage 1: K=64 GEMVs straight from global ----
    float acc1[8];
#pragma unroll
    for (int c = 0; c < 8; c++) acc1[c] = 0.f;
    if (wv < 2) {
        const float* src = H1 + (long)w * 8192 + ch;
#pragma unroll 4
        for (int j = 0; j < 64; j++) {
            float f = src[j * 128];
#pragma unroll
            for (int c = 0; c < 8; c++)
                acc1[c] = fmaf(rlane(mmL[c], j), f, acc1[c]);
        }
#pragma unroll
        for (int c = 0; c < 8; c++) sU[c * 129 + ch] = acc1[c];
    } else {
        const float* src = inF + (long)w * 8192 + ch;
#pragma unroll 4
        for (int j = 0; j < 64; j++) {
            float f = (src[j * 128] - mu) * rs;
#pragma unroll
            for (int c = 0; c < 8; c++)
                acc1[c] = fmaf(rlane(mmL[c], j), f, acc1[c]);
        }
#pragma unroll
        for (int c = 0; c < 8; c++) sT[c * 129 + ch] = acc1[c];
    }
    __syncthreads();
    // ---- stage 2: K=128 GEMVs with global weights ----
    float xL0[8], xL1[8];
    {
        const float* s2 = (wv < 2) ? sU : sT;
#pragma unroll
        for (int c = 0; c < 8; c++) {
            xL0[c] = s2[c * 129 + lane];
            xL1[c] = s2[c * 129 + 64 + lane];
        }
    }
    const float* Wm = (wv < 2) ? W2 : Wvf;
    float acc2[8];
#pragma unroll
    for (int c = 0; c < 8; c++) acc2[c] = 0.f;
#pragma unroll 2
    for (int k = 0; k < 64; k++) {
        float wk = Wm[k * 128 + ch];
#pragma unroll
        for (int c = 0; c < 8; c++)
            acc2[c] = fmaf(rlane(xL0[c], k), wk, acc2[c]);
    }
#pragma unroll 2
    for (int k = 0; k < 64; k++) {
        float wk = Wm[(k + 64) * 128 + ch];
#pragma unroll
        for (int c = 0; c < 8; c++)
            acc2[c] = fmaf(rlane(xL1[c], k), wk, acc2[c]);
    }
    if (wv >= 2) {
        // + t1 * sigma  (t1[c][ch] is this lane's own value)
        float sig = 1.0f / rs;
#pragma unroll
        for (int c = 0; c < 8; c++) {
            float t1ch = (wv & 1) ? xL1[c] : xL0[c];
            acc2[c] = fmaf(t1ch, sig, acc2[c]);
        }
#pragma unroll
        for (int c = 0; c < 8; c++) sP[c * 129 + ch] = acc2[c];
    }
    __syncthreads();
    if (wv < 2) {
        float scv[8];
#pragma unroll
        for (int c = 0; c < 8; c++) {
            float s = mmL[c];
            for (int off = 1; off < 64; off <<= 1) s += __shfl_xor(s, off);
            scv[c] = s;
        }
        float mub = mu + b2[ch];
        float bfv = bfc[ch];
#pragma unroll
        for (int c = 0; c < 8; c++) {
            float o = acc2[c] + sP[c * 129 + ch] + scv[c] * mub + bfv;
            oCLF[(long)w * 1024 + c * 128 + ch] = o;
        }
    }
}

// ---------------------------------------------------------------------------
extern "C" void kernel_launch(void* const* d_in, const int* in_sizes, int n_in,
                              void* d_out, int out_size, void* d_ws, size_t ws_size,
                              hipStream_t stream)
{
    (void)in_sizes; (void)n_in; (void)out_size; (void)ws_size;
    const float* in_f   = (const float*)d_in[0];
    const float* in_geo = (const float*)d_in[1];
    const float* W1  = (const float*)d_in[2];
    const float* b1  = (const float*)d_in[3];
    const float* W2  = (const float*)d_in[4];
    const float* b2  = (const float*)d_in[5];
    const float* Wfc = (const float*)d_in[6];
    const float* bfc = (const float*)d_in[7];
    const float* Wq  = (const float*)d_in[8];
    const float* Wv  = (const float*)d_in[9];
    float* out = (float*)d_out;
    float* ws  = (float*)d_ws;

    // workspace (floats)
    float* qh     = ws;                    // 16,777,216 (h1)
    float* clmm   = ws + 16777216;         //  1,048,576
    float* stats1 = ws + 17825792;         //  64
    float* stats2 = ws + 17825856;         //  64
    float* wvf    = ws + 17825920;         //  16,384
    float* part   = ws + 17842304;         //  8,192

    // output layout (floats)
    float* o_clf  = out;                   // (8,256,8,128)
    float* o_clm  = out + 2097152;         // (8,256,8,64)
    float* o_geo  = out + 3145728;         // (8,256,8,6)
    float* o_clr  = out + 3244032;         // (8,256,7,1)
    float* o_comp = out + 3258368;         // (8,256,8,1)
    float* o_af   = out + 3274752;         // (8,256,64,64)
    float* o_scm  = out + 11663360;        // (8,256,1,64)
    float* o_q    = out + 11794432;        // (8,256,64,128)

    gn_partial_k<<<dim3(64, 32), 256, 0, stream>>>(in_f, part);
    gn_final_k<<<32, 64, 0, stream>>>(part, stats1, 64);
    wvf_prep_k<<<32, 256, 0, stream>>>(Wv, Wfc, wvf);
    // h1 = leaky(gn1(in_f)@W1 + b1) -> qh;  qraw = gn1(in_f)@Wq -> o_q (+stats2 partials)
    gemm256_fused<<<1024, 256, 0, stream>>>(in_f, W1, b1, Wq, stats1, qh, o_q, part);
    gn_final_k<<<32, 64, 0, stream>>>(part, stats2, 128);
    // attn normalizes qraw IN PLACE in o_q and emits af
    attn_v2<<<1024, 256, 0, stream>>>(o_q, stats2, o_q, o_af);
    cluster_v3<<<2048, 256, 0, stream>>>(o_af, in_geo, o_clm, o_clr, o_comp, o_geo,
                                         o_scm, clmm);
    final_v3<<<2048, 256, 0, stream>>>(in_f, qh, clmm, stats1, W2, b2, wvf, bfc, o_clf);
}